// Round 8
// baseline (182.554 us; speedup 1.0000x reference)
//
#include <hip/hip_runtime.h>

typedef unsigned int  u32;
typedef unsigned short u16;
typedef short s16x8 __attribute__((ext_vector_type(8)));
typedef float f32x16 __attribute__((ext_vector_type(16)));

#define BB   4
#define CC   64
#define HH   128
#define WW   128
#define NWIN 64
#define PP   1024

// float -> bf16, round-to-nearest-even
__device__ __forceinline__ u16 f2bf(float f) {
  u32 x = __float_as_uint(f);
  return (u16)((x + 0x7fffu + ((x >> 16) & 1u)) >> 16);
}
__device__ __forceinline__ u32 pk2(float a, float b) {
  return (u32)f2bf(a) | ((u32)f2bf(b) << 16);
}

// ---------------------------------------------------------------------------
// Kernel 1: depthwise 7x7 conv + bias -> fp32 hw[n][c][p], bf16 vb[n][c][p],
// fp32 vsum[n][c] = sum_p hw (for P-1 trick). (unchanged from R7)
// ---------------------------------------------------------------------------
__global__ __launch_bounds__(256)
void dwconv_kernel(const float* __restrict__ x, const float* __restrict__ w,
                   const float* __restrict__ bias, float* __restrict__ hw,
                   u16* __restrict__ vb, float* __restrict__ vsum) {
  int blk = blockIdx.x;          // n*64 + c
  int n = blk >> 6, c = blk & 63;
  int b = n >> 4, wy = (n >> 2) & 3, wx = n & 3;
  int y0 = wy * 32 - 3, x0 = wx * 32 - 3;
  __shared__ float patch[38][40];   // row stride 160B (16B-aligned)
  __shared__ float wf[49];
  __shared__ float wsum[4];
  int tid = threadIdx.x;
  if (tid < 49) wf[tid] = w[c * 49 + tid];
  const float* xp = x + (size_t)(b * CC + c) * HH * WW;
  for (int i = tid; i < 38 * 38; i += 256) {
    int py = i / 38, px = i - py * 38;
    int gy = y0 + py, gx = x0 + px;
    float v = 0.f;
    if (gy >= 0 && gy < HH && gx >= 0 && gx < WW) v = xp[gy * WW + gx];
    patch[py][px] = v;
  }
  __syncthreads();
  float bv = bias[c];
  int yy = tid >> 3;            // output row 0..31
  int xg = (tid & 7) << 2;      // output col base 0,4,...,28
  float o0_ = bv, o1_ = bv, o2_ = bv, o3_ = bv;
  #pragma unroll
  for (int dy = 0; dy < 7; ++dy) {
    const float* pr = &patch[yy + dy][xg];
    float4 ra = *(const float4*)pr;
    float4 rb = *(const float4*)(pr + 4);
    float4 rc = *(const float4*)(pr + 8);
    float rv[12] = {ra.x, ra.y, ra.z, ra.w, rb.x, rb.y, rb.z, rb.w,
                    rc.x, rc.y, rc.z, rc.w};
    #pragma unroll
    for (int dx = 0; dx < 7; ++dx) {
      float wgt = wf[dy * 7 + dx];
      o0_ = fmaf(rv[dx],     wgt, o0_);
      o1_ = fmaf(rv[dx + 1], wgt, o1_);
      o2_ = fmaf(rv[dx + 2], wgt, o2_);
      o3_ = fmaf(rv[dx + 3], wgt, o3_);
    }
  }
  size_t obase = (size_t)(n * CC + c) * PP + yy * 32 + xg;
  *(float4*)(hw + obase) = make_float4(o0_, o1_, o2_, o3_);
  *(uint2*)(vb + obase) = make_uint2(pk2(o0_, o1_), pk2(o2_, o3_));
  float psum = (o0_ + o1_) + (o2_ + o3_);
  #pragma unroll
  for (int off = 1; off < 64; off <<= 1) psum += __shfl_xor(psum, off);
  if ((tid & 63) == 0) wsum[tid >> 6] = psum;
  __syncthreads();
  if (tid == 0) vsum[blk] = (wsum[0] + wsum[1]) + (wsum[2] + wsum[3]);
}

// ---------------------------------------------------------------------------
// Kernel 2 (MFMA, no LDS): q = 0.125*(W2 h + b2), k = W3 h + b3 -> bf16
// qT/kT[n][p][c]. Split-precision h (hi+lo bf16, 2 MFMAs). (unchanged from R7)
// ---------------------------------------------------------------------------
__global__ __launch_bounds__(256)
void qk_kernel(const float* __restrict__ hw,
               const float* __restrict__ w2, const float* __restrict__ b2,
               const float* __restrict__ w3, const float* __restrict__ b3,
               u16* __restrict__ qT, u16* __restrict__ kT) {
  int n = blockIdx.x >> 4;
  int chunk = blockIdx.x & 15;
  int tid = threadIdx.x;
  int lane = tid & 63, wvi = tid >> 6;
  int l31 = lane & 31, hi = lane >> 5;
  int phalf = wvi & 1, ochalf = wvi >> 1;
  int p0 = (chunk << 6) + (phalf << 5);
  int oc0 = ochalf << 5;

  union FU { u32 u[4]; s16x8 v; };

  s16x8 bq[4], bk[4];
  {
    const float* w2r = w2 + (oc0 + l31) * 64 + (hi << 3);
    const float* w3r = w3 + (oc0 + l31) * 64 + (hi << 3);
    #pragma unroll
    for (int kst = 0; kst < 4; ++kst) {
      float4 a = *(const float4*)(w2r + kst * 16);
      float4 b = *(const float4*)(w2r + kst * 16 + 4);
      FU f;
      f.u[0] = pk2(a.x * 0.125f, a.y * 0.125f);
      f.u[1] = pk2(a.z * 0.125f, a.w * 0.125f);
      f.u[2] = pk2(b.x * 0.125f, b.y * 0.125f);
      f.u[3] = pk2(b.z * 0.125f, b.w * 0.125f);
      bq[kst] = f.v;
      float4 c = *(const float4*)(w3r + kst * 16);
      float4 d = *(const float4*)(w3r + kst * 16 + 4);
      f.u[0] = pk2(c.x, c.y); f.u[1] = pk2(c.z, c.w);
      f.u[2] = pk2(d.x, d.y); f.u[3] = pk2(d.z, d.w);
      bk[kst] = f.v;
    }
  }

  f32x16 accq, acck;
  #pragma unroll
  for (int j = 0; j < 16; ++j) { accq[j] = 0.f; acck[j] = 0.f; }

  const float* hbase = hw + ((size_t)n << 16) + (size_t)(hi << 3) * PP
                       + p0 + l31;
  #pragma unroll
  for (int kst = 0; kst < 4; ++kst) {
    const float* hp = hbase + (size_t)(kst * 16) * PP;
    float h[8];
    #pragma unroll
    for (int e = 0; e < 8; ++e) h[e] = hp[e * PP];
    FU fh, fl;
    #pragma unroll
    for (int t = 0; t < 4; ++t) {
      u32 ph;
      asm("v_cvt_pk_bf16_f32 %0, %1, %2"
          : "=v"(ph) : "v"(h[2 * t]), "v"(h[2 * t + 1]));
      fh.u[t] = ph;
      float r0 = h[2 * t]     - __uint_as_float(ph << 16);
      float r1 = h[2 * t + 1] - __uint_as_float(ph & 0xffff0000u);
      u32 pl;
      asm("v_cvt_pk_bf16_f32 %0, %1, %2" : "=v"(pl) : "v"(r0), "v"(r1));
      fl.u[t] = pl;
    }
    accq = __builtin_amdgcn_mfma_f32_32x32x16_bf16(fh.v, bq[kst], accq, 0, 0, 0);
    accq = __builtin_amdgcn_mfma_f32_32x32x16_bf16(fl.v, bq[kst], accq, 0, 0, 0);
    acck = __builtin_amdgcn_mfma_f32_32x32x16_bf16(fh.v, bk[kst], acck, 0, 0, 0);
    acck = __builtin_amdgcn_mfma_f32_32x32x16_bf16(fl.v, bk[kst], acck, 0, 0, 0);
  }

  float biasq = b2[oc0 + l31] * 0.125f;
  float biask = b3[oc0 + l31];
  u16* qrow = qT + (((size_t)n << 10) + p0) * 64 + oc0 + l31;
  u16* krow = kT + (((size_t)n << 10) + p0) * 64 + oc0 + l31;
  #pragma unroll
  for (int r = 0; r < 16; ++r) {
    int pr = (r & 3) + ((r >> 2) << 3) + (hi << 2);
    qrow[pr * 64] = f2bf(accq[r] + biasq);
    krow[pr * 64] = f2bf(acck[r] + biask);
  }
}

// ---------------------------------------------------------------------------
// Kernel 3: ZERO-LDS bf16 MFMA attention (P-1 decomposition) + fused conv4.
// Q frags preloaded to registers (constant over pt loop). K/V frags loaded
// per-lane DIRECTLY from global (L1-hot: 8KB K + 8KB V per tile, shared by
// all 4 waves; XCD swizzle keeps a window's 8 blocks on one XCD L2).
// Operand bits identical to the former LDS path -> bitwise-same results.
// No barriers in the main loop. LDS only: 16KB epilogue O-buffer + l_inv.
// ---------------------------------------------------------------------------
__global__ __launch_bounds__(256)
void attn_kernel(const u16* __restrict__ qT, const u16* __restrict__ kT,
                 const u16* __restrict__ vB, const float* __restrict__ vsum,
                 const float* __restrict__ w4, const float* __restrict__ b4,
                 float* __restrict__ outp) {
  int bid = blockIdx.x;
  int w = (bid & 7) * 64 + (bid >> 3);
  int n = w >> 3, qb = w & 7;
  int tid = threadIdx.x;

  __shared__ __align__(16) unsigned char Osm[16384];  // O[q=128][c=64] bf16
  __shared__ float l_inv[4][32];

  int lane = tid & 63, wv = tid >> 6;
  int l31 = lane & 31, hi = lane >> 5;

  const size_t nbase = (size_t)n << 16;   // n * 1024 * 64

  // ---- Q fragments once into registers (B-operand of S-MFMA) ----
  s16x8 qf[4];
  {
    const u16* qp = qT + nbase
                    + (size_t)((qb << 7) + (wv << 5) + l31) * 64 + (hi << 3);
    #pragma unroll
    for (int kc = 0; kc < 4; ++kc) qf[kc] = *(const s16x8*)(qp + kc * 16);
  }

  f32x16 o0, o1;
  #pragma unroll
  for (int j = 0; j < 16; ++j) { o0[j] = 0.f; o1[j] = 0.f; }
  float lsum = 0.f;

  const u16* kg = kT + nbase;
  const u16* vg = vB + nbase;

  for (int pt = 0; pt < 16; ++pt) {
    int p0 = pt << 6;

    // ---- K frags direct from global: rows p0+l31 / p0+32+l31 ----
    const u16* k0p = kg + (size_t)(p0 + l31) * 64 + (hi << 3);
    s16x8 kf0[4], kf1[4];
    #pragma unroll
    for (int kc = 0; kc < 4; ++kc) {
      kf0[kc] = *(const s16x8*)(k0p + kc * 16);
      kf1[kc] = *(const s16x8*)(k0p + 2048 + kc * 16);   // +32 rows * 64
    }

    // ---- S = K^T Q ----
    f32x16 s0, s1;
    #pragma unroll
    for (int j = 0; j < 16; ++j) { s0[j] = 0.f; s1[j] = 0.f; }
    #pragma unroll
    for (int kc = 0; kc < 4; ++kc) {
      s0 = __builtin_amdgcn_mfma_f32_32x32x16_bf16(kf0[kc], qf[kc], s0, 0, 0, 0);
      s1 = __builtin_amdgcn_mfma_f32_32x32x16_bf16(kf1[kc], qf[kc], s1, 0, 0, 0);
    }

    // ---- P_dev = exp(S)-1 ; l += exp(S) ----
    #pragma unroll
    for (int j = 0; j < 16; ++j) {
      float e = __expf(s0[j]); lsum += e; s0[j] = e - 1.0f;
    }
    #pragma unroll
    for (int j = 0; j < 16; ++j) {
      float e = __expf(s1[j]); lsum += e; s1[j] = e - 1.0f;
    }

    // ---- pack P_dev -> bf16 A-fragments of P_dev^T ----
    u32 t0,t1,t2,t3,t4,t5,t6,t7, u0,u1,u2,u3,u4,u5,u6,u7;
#define CVT(d, a, b) asm("v_cvt_pk_bf16_f32 %0, %1, %2" : "=v"(d) : "v"(a), "v"(b))
#define SWP(a, b)    asm("v_permlane32_swap_b32 %0, %1" : "+v"(a), "+v"(b))
    CVT(t0, s0[0],  s0[1]);  CVT(t1, s0[2],  s0[3]);
    CVT(t2, s0[4],  s0[5]);  CVT(t3, s0[6],  s0[7]);
    CVT(t4, s0[8],  s0[9]);  CVT(t5, s0[10], s0[11]);
    CVT(t6, s0[12], s0[13]); CVT(t7, s0[14], s0[15]);
    SWP(t0, t2); SWP(t1, t3); SWP(t4, t6); SWP(t5, t7);
    CVT(u0, s1[0],  s1[1]);  CVT(u1, s1[2],  s1[3]);
    CVT(u2, s1[4],  s1[5]);  CVT(u3, s1[6],  s1[7]);
    CVT(u4, s1[8],  s1[9]);  CVT(u5, s1[10], s1[11]);
    CVT(u6, s1[12], s1[13]); CVT(u7, s1[14], s1[15]);
    SWP(u0, u2); SWP(u1, u3); SWP(u4, u6); SWP(u5, u7);
#undef CVT
#undef SWP
    union FU { u32 u[4]; s16x8 v; };
    FU fA; fA.u[0]=t0; fA.u[1]=t1; fA.u[2]=t2; fA.u[3]=t3;  // p 0..15
    FU fB; fB.u[0]=t4; fB.u[1]=t5; fB.u[2]=t6; fB.u[3]=t7;  // p 16..31
    FU fC; fC.u[0]=u0; fC.u[1]=u1; fC.u[2]=u2; fC.u[3]=u3;  // p 32..47
    FU fD; fD.u[0]=u4; fD.u[1]=u5; fD.u[2]=u6; fD.u[3]=u7;  // p 48..63

    // ---- O^T += P_dev^T @ V^T ; V frags direct from global ----
    const u16* v0p = vg + (size_t)l31 * 1024 + p0 + (hi << 3);
#define PV_STEP(frag, ps) do { \
      s16x8 bv0 = *(const s16x8*)(v0p + (ps) * 16); \
      s16x8 bv1 = *(const s16x8*)(v0p + 32768 + (ps) * 16); \
      o0 = __builtin_amdgcn_mfma_f32_32x32x16_bf16(frag, bv0, o0, 0, 0, 0); \
      o1 = __builtin_amdgcn_mfma_f32_32x32x16_bf16(frag, bv1, o1, 0, 0, 0); \
    } while (0)
    PV_STEP(fA.v, 0);
    PV_STEP(fB.v, 1);
    PV_STEP(fC.v, 2);
    PV_STEP(fD.v, 3);
#undef PV_STEP
  }

  // ---- softmax denominator ----
  lsum += __shfl_xor(lsum, 32);
  if (hi == 0) l_inv[wv][l31] = 1.0f / lsum;

  // ---- O_final = (vsum + o)/l as bf16 into Osm (wave-private rows) ----
  float vs0 = vsum[(n << 6) + l31];
  float vs1 = vsum[(n << 6) + 32 + l31];
  int g0 = l31 >> 3, g1 = (32 + l31) >> 3;
  int bi = (l31 & 7) << 1;
  #pragma unroll
  for (int r = 0; r < 16; ++r) {
    int qr = (r & 3) + ((r >> 2) << 3) + (hi << 2);
    int row = (wv << 5) + qr;
    float li = l_inv[wv][qr];
    int rs = (row & 7) << 4;
    *(u16*)(Osm + row * 128 + ((g0 << 4) ^ rs) + bi) = f2bf((vs0 + o0[r]) * li);
    *(u16*)(Osm + row * 128 + ((g1 << 4) ^ rs) + bi) = f2bf((vs1 + o1[r]) * li);
  }
  // no barrier: each wave reads only its own rows below

  // ---- fused conv4: D2[oc][q] = sum_c W4[oc][c] * Ofinal[q][c] ----
  union FU2 { u32 u[4]; s16x8 v; };
  int orow = (wv << 5) + l31;
  int osw = (orow & 7) << 4;
  s16x8 bf[4];
  #pragma unroll
  for (int kst = 0; kst < 4; ++kst)
    bf[kst] = *(const s16x8*)(Osm + orow * 128 + ((((kst << 1) + hi) << 4) ^ osw));

  f32x16 d2a, d2b;
  #pragma unroll
  for (int j = 0; j < 16; ++j) { d2a[j] = 0.f; d2b[j] = 0.f; }
  {
    const float* w4r = w4 + l31 * 64 + (hi << 3);          // oc-half 0
    #pragma unroll
    for (int kst = 0; kst < 4; ++kst) {
      float4 a = *(const float4*)(w4r + kst * 16);
      float4 b = *(const float4*)(w4r + kst * 16 + 4);
      FU2 f;
      f.u[0] = pk2(a.x, a.y); f.u[1] = pk2(a.z, a.w);
      f.u[2] = pk2(b.x, b.y); f.u[3] = pk2(b.z, b.w);
      d2a = __builtin_amdgcn_mfma_f32_32x32x16_bf16(f.v, bf[kst], d2a, 0, 0, 0);
    }
    const float* w4r2 = w4 + (32 + l31) * 64 + (hi << 3);  // oc-half 1
    #pragma unroll
    for (int kst = 0; kst < 4; ++kst) {
      float4 a = *(const float4*)(w4r2 + kst * 16);
      float4 b = *(const float4*)(w4r2 + kst * 16 + 4);
      FU2 f;
      f.u[0] = pk2(a.x, a.y); f.u[1] = pk2(a.z, a.w);
      f.u[2] = pk2(b.x, b.y); f.u[3] = pk2(b.z, b.w);
      d2b = __builtin_amdgcn_mfma_f32_32x32x16_bf16(f.v, bf[kst], d2b, 0, 0, 0);
    }
  }

  // ---- store NCHW: p = qb*128 + wv*32 + l31 -> y fixed/wave, x = wx*32+l31
  int b_ = n >> 4, wy = (n >> 2) & 3, wx = n & 3;
  int y = wy * 32 + (qb << 2) + wv;
  int x = wx * 32 + l31;
  float* obase = outp + ((size_t)b_ * CC * HH + y) * WW + x;
  #pragma unroll
  for (int r = 0; r < 16; ++r) {
    int ocr = (r & 3) + ((r >> 2) << 3) + (hi << 2);
    obase[(size_t)ocr * HH * WW]        = d2a[r] + b4[ocr];
    obase[(size_t)(32 + ocr) * HH * WW] = d2b[r] + b4[32 + ocr];
  }
}

// ---------------------------------------------------------------------------
extern "C" void kernel_launch(void* const* d_in, const int* in_sizes, int n_in,
                              void* d_out, int out_size, void* d_ws, size_t ws_size,
                              hipStream_t stream) {
  const float* x  = (const float*)d_in[0];
  const float* w1 = (const float*)d_in[1];
  const float* b1 = (const float*)d_in[2];
  const float* w2 = (const float*)d_in[3];
  const float* b2 = (const float*)d_in[4];
  const float* w3 = (const float*)d_in[5];
  const float* b3 = (const float*)d_in[6];
  const float* w4 = (const float*)d_in[7];
  const float* b4 = (const float*)d_in[8];
  float* outp = (float*)d_out;

  char* wsb = (char*)d_ws;
  float* hw   = (float*)wsb;                       // 16 MiB fp32 [n][c][p]
  u16*   qT   = (u16*)(wsb + (16u << 20));         //  8 MiB bf16 [n][p][c]
  u16*   kT   = (u16*)(wsb + (24u << 20));         //  8 MiB bf16 [n][p][c]
  u16*   vb   = (u16*)(wsb + (32u << 20));         //  8 MiB bf16 [n][c][p]
  float* vsum = (float*)(wsb + (40u << 20));       // 16 KiB fp32 [n][c]

  dwconv_kernel<<<NWIN * CC, 256, 0, stream>>>(x, w1, b1, hw, vb, vsum);
  qk_kernel   <<<NWIN * 16, 256, 0, stream>>>(hw, w2, b2, w3, b3, qT, kT);
  attn_kernel <<<NWIN * 8,  256, 0, stream>>>(qT, kT, vb, vsum, w4, b4, outp);
}

// Round 9
// 145.213 us; speedup vs baseline: 1.2571x; 1.2571x over previous
//
#include <hip/hip_runtime.h>

typedef unsigned int  u32;
typedef unsigned short u16;
typedef short s16x8 __attribute__((ext_vector_type(8)));
typedef float f32x16 __attribute__((ext_vector_type(16)));

#define BB   4
#define CC   64
#define HH   128
#define WW   128
#define NWIN 64
#define PP   1024

// float -> bf16, round-to-nearest-even
__device__ __forceinline__ u16 f2bf(float f) {
  u32 x = __float_as_uint(f);
  return (u16)((x + 0x7fffu + ((x >> 16) & 1u)) >> 16);
}
__device__ __forceinline__ u32 pk2(float a, float b) {
  return (u32)f2bf(a) | ((u32)f2bf(b) << 16);
}

// ---------------------------------------------------------------------------
// Kernel 1: depthwise 7x7 conv + bias -> fp32 hw[n][c][p], bf16 vb[n][c][p],
// fp32 vsum[n][c] = sum_p hw (for P-1 trick). (unchanged, proven)
// ---------------------------------------------------------------------------
__global__ __launch_bounds__(256)
void dwconv_kernel(const float* __restrict__ x, const float* __restrict__ w,
                   const float* __restrict__ bias, float* __restrict__ hw,
                   u16* __restrict__ vb, float* __restrict__ vsum) {
  int blk = blockIdx.x;          // n*64 + c
  int n = blk >> 6, c = blk & 63;
  int b = n >> 4, wy = (n >> 2) & 3, wx = n & 3;
  int y0 = wy * 32 - 3, x0 = wx * 32 - 3;
  __shared__ float patch[38][40];   // row stride 160B (16B-aligned)
  __shared__ float wf[49];
  __shared__ float wsum[4];
  int tid = threadIdx.x;
  if (tid < 49) wf[tid] = w[c * 49 + tid];
  const float* xp = x + (size_t)(b * CC + c) * HH * WW;
  for (int i = tid; i < 38 * 38; i += 256) {
    int py = i / 38, px = i - py * 38;
    int gy = y0 + py, gx = x0 + px;
    float v = 0.f;
    if (gy >= 0 && gy < HH && gx >= 0 && gx < WW) v = xp[gy * WW + gx];
    patch[py][px] = v;
  }
  __syncthreads();
  float bv = bias[c];
  int yy = tid >> 3;            // output row 0..31
  int xg = (tid & 7) << 2;      // output col base 0,4,...,28
  float o0_ = bv, o1_ = bv, o2_ = bv, o3_ = bv;
  #pragma unroll
  for (int dy = 0; dy < 7; ++dy) {
    const float* pr = &patch[yy + dy][xg];
    float4 ra = *(const float4*)pr;
    float4 rb = *(const float4*)(pr + 4);
    float4 rc = *(const float4*)(pr + 8);
    float rv[12] = {ra.x, ra.y, ra.z, ra.w, rb.x, rb.y, rb.z, rb.w,
                    rc.x, rc.y, rc.z, rc.w};
    #pragma unroll
    for (int dx = 0; dx < 7; ++dx) {
      float wgt = wf[dy * 7 + dx];
      o0_ = fmaf(rv[dx],     wgt, o0_);
      o1_ = fmaf(rv[dx + 1], wgt, o1_);
      o2_ = fmaf(rv[dx + 2], wgt, o2_);
      o3_ = fmaf(rv[dx + 3], wgt, o3_);
    }
  }
  size_t obase = (size_t)(n * CC + c) * PP + yy * 32 + xg;
  *(float4*)(hw + obase) = make_float4(o0_, o1_, o2_, o3_);
  *(uint2*)(vb + obase) = make_uint2(pk2(o0_, o1_), pk2(o2_, o3_));
  float psum = (o0_ + o1_) + (o2_ + o3_);
  #pragma unroll
  for (int off = 1; off < 64; off <<= 1) psum += __shfl_xor(psum, off);
  if ((tid & 63) == 0) wsum[tid >> 6] = psum;
  __syncthreads();
  if (tid == 0) vsum[blk] = (wsum[0] + wsum[1]) + (wsum[2] + wsum[3]);
}

// ---------------------------------------------------------------------------
// Kernel 2 (MFMA, no LDS): q = 0.125*(W2 h + b2), k = W3 h + b3 -> bf16
// qT/kT[n][p][c]. Split-precision h (hi+lo bf16, 2 MFMAs). (unchanged, proven)
// ---------------------------------------------------------------------------
__global__ __launch_bounds__(256)
void qk_kernel(const float* __restrict__ hw,
               const float* __restrict__ w2, const float* __restrict__ b2,
               const float* __restrict__ w3, const float* __restrict__ b3,
               u16* __restrict__ qT, u16* __restrict__ kT) {
  int n = blockIdx.x >> 4;
  int chunk = blockIdx.x & 15;
  int tid = threadIdx.x;
  int lane = tid & 63, wvi = tid >> 6;
  int l31 = lane & 31, hi = lane >> 5;
  int phalf = wvi & 1, ochalf = wvi >> 1;
  int p0 = (chunk << 6) + (phalf << 5);
  int oc0 = ochalf << 5;

  union FU { u32 u[4]; s16x8 v; };

  s16x8 bq[4], bk[4];
  {
    const float* w2r = w2 + (oc0 + l31) * 64 + (hi << 3);
    const float* w3r = w3 + (oc0 + l31) * 64 + (hi << 3);
    #pragma unroll
    for (int kst = 0; kst < 4; ++kst) {
      float4 a = *(const float4*)(w2r + kst * 16);
      float4 b = *(const float4*)(w2r + kst * 16 + 4);
      FU f;
      f.u[0] = pk2(a.x * 0.125f, a.y * 0.125f);
      f.u[1] = pk2(a.z * 0.125f, a.w * 0.125f);
      f.u[2] = pk2(b.x * 0.125f, b.y * 0.125f);
      f.u[3] = pk2(b.z * 0.125f, b.w * 0.125f);
      bq[kst] = f.v;
      float4 c = *(const float4*)(w3r + kst * 16);
      float4 d = *(const float4*)(w3r + kst * 16 + 4);
      f.u[0] = pk2(c.x, c.y); f.u[1] = pk2(c.z, c.w);
      f.u[2] = pk2(d.x, d.y); f.u[3] = pk2(d.z, d.w);
      bk[kst] = f.v;
    }
  }

  f32x16 accq, acck;
  #pragma unroll
  for (int j = 0; j < 16; ++j) { accq[j] = 0.f; acck[j] = 0.f; }

  const float* hbase = hw + ((size_t)n << 16) + (size_t)(hi << 3) * PP
                       + p0 + l31;
  #pragma unroll
  for (int kst = 0; kst < 4; ++kst) {
    const float* hp = hbase + (size_t)(kst * 16) * PP;
    float h[8];
    #pragma unroll
    for (int e = 0; e < 8; ++e) h[e] = hp[e * PP];
    FU fh, fl;
    #pragma unroll
    for (int t = 0; t < 4; ++t) {
      u32 ph;
      asm("v_cvt_pk_bf16_f32 %0, %1, %2"
          : "=v"(ph) : "v"(h[2 * t]), "v"(h[2 * t + 1]));
      fh.u[t] = ph;
      float r0 = h[2 * t]     - __uint_as_float(ph << 16);
      float r1 = h[2 * t + 1] - __uint_as_float(ph & 0xffff0000u);
      u32 pl;
      asm("v_cvt_pk_bf16_f32 %0, %1, %2" : "=v"(pl) : "v"(r0), "v"(r1));
      fl.u[t] = pl;
    }
    accq = __builtin_amdgcn_mfma_f32_32x32x16_bf16(fh.v, bq[kst], accq, 0, 0, 0);
    accq = __builtin_amdgcn_mfma_f32_32x32x16_bf16(fl.v, bq[kst], accq, 0, 0, 0);
    acck = __builtin_amdgcn_mfma_f32_32x32x16_bf16(fh.v, bk[kst], acck, 0, 0, 0);
    acck = __builtin_amdgcn_mfma_f32_32x32x16_bf16(fl.v, bk[kst], acck, 0, 0, 0);
  }

  float biasq = b2[oc0 + l31] * 0.125f;
  float biask = b3[oc0 + l31];
  u16* qrow = qT + (((size_t)n << 10) + p0) * 64 + oc0 + l31;
  u16* krow = kT + (((size_t)n << 10) + p0) * 64 + oc0 + l31;
  #pragma unroll
  for (int r = 0; r < 16; ++r) {
    int pr = (r & 3) + ((r >> 2) << 3) + (hi << 2);
    qrow[pr * 64] = f2bf(accq[r] + biasq);
    krow[pr * 64] = f2bf(acck[r] + biask);
  }
}

// ---------------------------------------------------------------------------
// Kernel 3: LDS bf16 MFMA attention (P-1 decomposition) + fused conv4.
// R7 structure + (a) Q fragments hoisted to registers (R8-proven bits; drops
// QsB and 4 LDS reads/pt/wave), (b) double-buffered K/V with async-split
// staging: issue tile t+1 global loads BEFORE compute of t, ds_write to the
// alternate buffer after compute, ONE barrier per pt.
// Race-free invariant: reads of buf X at iter t drain at barrier t; writes to
// X happen only at iter t+1 (after that barrier).
// Operand bits and MFMA order identical to R7 -> bitwise-same results.
// ---------------------------------------------------------------------------
__global__ __launch_bounds__(256)
void attn_kernel(const u16* __restrict__ qT, const u16* __restrict__ kT,
                 const u16* __restrict__ vB, const float* __restrict__ vsum,
                 const float* __restrict__ w4, const float* __restrict__ b4,
                 float* __restrict__ outp) {
  int bid = blockIdx.x;
  int w = (bid & 7) * 64 + (bid >> 3);
  int n = w >> 3, qb = w & 7;
  int tid = threadIdx.x;

  __shared__ __align__(16) unsigned char KsB[2][8192];  // K^T[p=64][c=64] dbuf
  __shared__ __align__(16) unsigned char VsB[2][8192];  // V[c=64][p=64] dbuf
  __shared__ __align__(16) unsigned char Osm[16384];    // O[q=128][c=64] bf16
  __shared__ float l_inv[4][32];

  int lane = tid & 63, wv = tid >> 6;
  int l31 = lane & 31, hi = lane >> 5;
  int sz = (lane & 7) << 4;
  int hi16 = hi << 4;

  const size_t nbase = (size_t)n << 16;   // n * 1024 * 64
  const u16* kg = kT + nbase;
  const u16* vg = vB + nbase;

  // ---- Q fragments once into registers (B-operand of S-MFMA) ----
  s16x8 qf[4];
  {
    const u16* qp = qT + nbase
                    + (size_t)((qb << 7) + (wv << 5) + l31) * 64 + (hi << 3);
    #pragma unroll
    for (int kc = 0; kc < 4; ++kc) qf[kc] = *(const s16x8*)(qp + kc * 16);
  }

  // ---- per-thread staging slots (2 x 16B for K, 2 x 16B for V) ----
  int i0 = tid, i1 = tid + 256;
  int row0 = i0 >> 3, c80 = i0 & 7;
  int row1 = i1 >> 3, c81 = i1 & 7;
  int dst0 = row0 * 128 + ((c80 * 16) ^ ((row0 & 7) << 4));
  int dst1 = row1 * 128 + ((c81 * 16) ^ ((row1 & 7) << 4));
  const u16* ks0 = kg + (size_t)row0 * 64 + c80 * 8;
  const u16* ks1 = kg + (size_t)row1 * 64 + c81 * 8;
  const u16* vs0 = vg + (size_t)row0 * 1024 + c80 * 8;
  const u16* vs1 = vg + (size_t)row1 * 1024 + c81 * 8;

  // ---- prologue: stage tile 0 into buffer 0 ----
  {
    uint4 ka = *(const uint4*)ks0;
    uint4 kb = *(const uint4*)ks1;
    uint4 va = *(const uint4*)vs0;
    uint4 vbx = *(const uint4*)vs1;
    *(uint4*)(KsB[0] + dst0) = ka;
    *(uint4*)(KsB[0] + dst1) = kb;
    *(uint4*)(VsB[0] + dst0) = va;
    *(uint4*)(VsB[0] + dst1) = vbx;
  }
  __syncthreads();

  f32x16 o0, o1;
  #pragma unroll
  for (int j = 0; j < 16; ++j) { o0[j] = 0.f; o1[j] = 0.f; }
  float lsum = 0.f;

  int cur = 0;
  for (int pt = 0; pt < 16; ++pt) {
    // ---- issue next-tile global loads early (latency hides under compute) --
    uint4 ka, kb, va, vbx;
    if (pt < 15) {
      size_t pn = (size_t)((pt + 1) << 6);
      ka  = *(const uint4*)(ks0 + pn * 64);
      kb  = *(const uint4*)(ks1 + pn * 64);
      va  = *(const uint4*)(vs0 + pn);
      vbx = *(const uint4*)(vs1 + pn);
    }

    const unsigned char* Kc = KsB[cur];
    const unsigned char* Vc = VsB[cur];

    // ---- S = K^T Q : two 32-p chunks ----
    f32x16 s0, s1;
    #pragma unroll
    for (int j = 0; j < 16; ++j) { s0[j] = 0.f; s1[j] = 0.f; }
    #pragma unroll
    for (int kc = 0; kc < 4; ++kc) {
      int cb = kc * 32 + hi16;
      s16x8 a0 = *(const s16x8*)(Kc + l31 * 128 + (cb ^ sz));
      s16x8 a1 = *(const s16x8*)(Kc + (32 + l31) * 128 + (cb ^ sz));
      s0 = __builtin_amdgcn_mfma_f32_32x32x16_bf16(a0, qf[kc], s0, 0, 0, 0);
      s1 = __builtin_amdgcn_mfma_f32_32x32x16_bf16(a1, qf[kc], s1, 0, 0, 0);
    }

    // ---- P_dev = exp(S)-1 ; l += exp(S) ----
    #pragma unroll
    for (int j = 0; j < 16; ++j) {
      float e = __expf(s0[j]); lsum += e; s0[j] = e - 1.0f;
    }
    #pragma unroll
    for (int j = 0; j < 16; ++j) {
      float e = __expf(s1[j]); lsum += e; s1[j] = e - 1.0f;
    }

    // ---- pack P_dev -> bf16 A-fragments of P_dev^T ----
    u32 t0,t1,t2,t3,t4,t5,t6,t7, u0,u1,u2,u3,u4,u5,u6,u7;
#define CVT(d, a, b) asm("v_cvt_pk_bf16_f32 %0, %1, %2" : "=v"(d) : "v"(a), "v"(b))
#define SWP(a, b)    asm("v_permlane32_swap_b32 %0, %1" : "+v"(a), "+v"(b))
    CVT(t0, s0[0],  s0[1]);  CVT(t1, s0[2],  s0[3]);
    CVT(t2, s0[4],  s0[5]);  CVT(t3, s0[6],  s0[7]);
    CVT(t4, s0[8],  s0[9]);  CVT(t5, s0[10], s0[11]);
    CVT(t6, s0[12], s0[13]); CVT(t7, s0[14], s0[15]);
    SWP(t0, t2); SWP(t1, t3); SWP(t4, t6); SWP(t5, t7);
    CVT(u0, s1[0],  s1[1]);  CVT(u1, s1[2],  s1[3]);
    CVT(u2, s1[4],  s1[5]);  CVT(u3, s1[6],  s1[7]);
    CVT(u4, s1[8],  s1[9]);  CVT(u5, s1[10], s1[11]);
    CVT(u6, s1[12], s1[13]); CVT(u7, s1[14], s1[15]);
    SWP(u0, u2); SWP(u1, u3); SWP(u4, u6); SWP(u5, u7);
#undef CVT
#undef SWP
    union FU { u32 u[4]; s16x8 v; };
    FU fA; fA.u[0]=t0; fA.u[1]=t1; fA.u[2]=t2; fA.u[3]=t3;  // p 0..15
    FU fB; fB.u[0]=t4; fB.u[1]=t5; fB.u[2]=t6; fB.u[3]=t7;  // p 16..31
    FU fC; fC.u[0]=u0; fC.u[1]=u1; fC.u[2]=u2; fC.u[3]=u3;  // p 32..47
    FU fD; fD.u[0]=u4; fD.u[1]=u5; fD.u[2]=u6; fD.u[3]=u7;  // p 48..63

    // ---- O^T += P_dev^T @ V^T ----
#define PV_STEP(frag, pb) do { \
      s16x8 bv0 = *(const s16x8*)(Vc + l31 * 128 + ((pb) ^ sz)); \
      s16x8 bv1 = *(const s16x8*)(Vc + (32 + l31) * 128 + ((pb) ^ sz)); \
      o0 = __builtin_amdgcn_mfma_f32_32x32x16_bf16(frag, bv0, o0, 0, 0, 0); \
      o1 = __builtin_amdgcn_mfma_f32_32x32x16_bf16(frag, bv1, o1, 0, 0, 0); \
    } while (0)
    PV_STEP(fA.v, 0 + hi16);
    PV_STEP(fB.v, 32 + hi16);
    PV_STEP(fC.v, 64 + hi16);
    PV_STEP(fD.v, 96 + hi16);
#undef PV_STEP

    // ---- write next tile into alternate buffer, single barrier ----
    if (pt < 15) {
      *(uint4*)(KsB[cur ^ 1] + dst0) = ka;
      *(uint4*)(KsB[cur ^ 1] + dst1) = kb;
      *(uint4*)(VsB[cur ^ 1] + dst0) = va;
      *(uint4*)(VsB[cur ^ 1] + dst1) = vbx;
      __syncthreads();
      cur ^= 1;
    }
  }

  // ---- softmax denominator ----
  lsum += __shfl_xor(lsum, 32);
  if (hi == 0) l_inv[wv][l31] = 1.0f / lsum;

  // ---- O_final = (vsum + o)/l as bf16 into Osm (wave-private rows) ----
  float vsa = vsum[(n << 6) + l31];
  float vsb = vsum[(n << 6) + 32 + l31];
  int g0 = l31 >> 3, g1 = (32 + l31) >> 3;
  int bi = (l31 & 7) << 1;
  #pragma unroll
  for (int r = 0; r < 16; ++r) {
    int qr = (r & 3) + ((r >> 2) << 3) + (hi << 2);
    int row = (wv << 5) + qr;
    float li = l_inv[wv][qr];
    int rs = (row & 7) << 4;
    *(u16*)(Osm + row * 128 + ((g0 << 4) ^ rs) + bi) = f2bf((vsa + o0[r]) * li);
    *(u16*)(Osm + row * 128 + ((g1 << 4) ^ rs) + bi) = f2bf((vsb + o1[r]) * li);
  }
  // no barrier: each wave reads only its own rows below

  // ---- fused conv4: D2[oc][q] = sum_c W4[oc][c] * Ofinal[q][c] ----
  union FU2 { u32 u[4]; s16x8 v; };
  int orow = (wv << 5) + l31;
  int osw = (orow & 7) << 4;
  s16x8 bf[4];
  #pragma unroll
  for (int kst = 0; kst < 4; ++kst)
    bf[kst] = *(const s16x8*)(Osm + orow * 128 + ((((kst << 1) + hi) << 4) ^ osw));

  f32x16 d2a, d2b;
  #pragma unroll
  for (int j = 0; j < 16; ++j) { d2a[j] = 0.f; d2b[j] = 0.f; }
  {
    const float* w4r = w4 + l31 * 64 + (hi << 3);          // oc-half 0
    #pragma unroll
    for (int kst = 0; kst < 4; ++kst) {
      float4 a = *(const float4*)(w4r + kst * 16);
      float4 b = *(const float4*)(w4r + kst * 16 + 4);
      FU2 f;
      f.u[0] = pk2(a.x, a.y); f.u[1] = pk2(a.z, a.w);
      f.u[2] = pk2(b.x, b.y); f.u[3] = pk2(b.z, b.w);
      d2a = __builtin_amdgcn_mfma_f32_32x32x16_bf16(f.v, bf[kst], d2a, 0, 0, 0);
    }
    const float* w4r2 = w4 + (32 + l31) * 64 + (hi << 3);  // oc-half 1
    #pragma unroll
    for (int kst = 0; kst < 4; ++kst) {
      float4 a = *(const float4*)(w4r2 + kst * 16);
      float4 b = *(const float4*)(w4r2 + kst * 16 + 4);
      FU2 f;
      f.u[0] = pk2(a.x, a.y); f.u[1] = pk2(a.z, a.w);
      f.u[2] = pk2(b.x, b.y); f.u[3] = pk2(b.z, b.w);
      d2b = __builtin_amdgcn_mfma_f32_32x32x16_bf16(f.v, bf[kst], d2b, 0, 0, 0);
    }
  }

  // ---- store NCHW: p = qb*128 + wv*32 + l31 -> y fixed/wave, x = wx*32+l31
  int b_ = n >> 4, wy = (n >> 2) & 3, wx = n & 3;
  int y = wy * 32 + (qb << 2) + wv;
  int x = wx * 32 + l31;
  float* obase = outp + ((size_t)b_ * CC * HH + y) * WW + x;
  #pragma unroll
  for (int r = 0; r < 16; ++r) {
    int ocr = (r & 3) + ((r >> 2) << 3) + (hi << 2);
    obase[(size_t)ocr * HH * WW]        = d2a[r] + b4[ocr];
    obase[(size_t)(32 + ocr) * HH * WW] = d2b[r] + b4[32 + ocr];
  }
}

// ---------------------------------------------------------------------------
extern "C" void kernel_launch(void* const* d_in, const int* in_sizes, int n_in,
                              void* d_out, int out_size, void* d_ws, size_t ws_size,
                              hipStream_t stream) {
  const float* x  = (const float*)d_in[0];
  const float* w1 = (const float*)d_in[1];
  const float* b1 = (const float*)d_in[2];
  const float* w2 = (const float*)d_in[3];
  const float* b2 = (const float*)d_in[4];
  const float* w3 = (const float*)d_in[5];
  const float* b3 = (const float*)d_in[6];
  const float* w4 = (const float*)d_in[7];
  const float* b4 = (const float*)d_in[8];
  float* outp = (float*)d_out;

  char* wsb = (char*)d_ws;
  float* hw   = (float*)wsb;                       // 16 MiB fp32 [n][c][p]
  u16*   qT   = (u16*)(wsb + (16u << 20));         //  8 MiB bf16 [n][p][c]
  u16*   kT   = (u16*)(wsb + (24u << 20));         //  8 MiB bf16 [n][p][c]
  u16*   vb   = (u16*)(wsb + (32u << 20));         //  8 MiB bf16 [n][c][p]
  float* vsum = (float*)(wsb + (40u << 20));       // 16 KiB fp32 [n][c]

  dwconv_kernel<<<NWIN * CC, 256, 0, stream>>>(x, w1, b1, hw, vb, vsum);
  qk_kernel   <<<NWIN * 16, 256, 0, stream>>>(hw, w2, b2, w3, b3, qT, kT);
  attn_kernel <<<NWIN * 8,  256, 0, stream>>>(qT, kT, vb, vsum, w4, b4, outp);
}

// Round 10
// 139.949 us; speedup vs baseline: 1.3044x; 1.0376x over previous
//
#include <hip/hip_runtime.h>

typedef unsigned int  u32;
typedef unsigned short u16;
typedef short s16x8 __attribute__((ext_vector_type(8)));
typedef float f32x16 __attribute__((ext_vector_type(16)));

#define BB   4
#define CC   64
#define HH   128
#define WW   128
#define NWIN 64
#define PP   1024

// float -> bf16, round-to-nearest-even
__device__ __forceinline__ u16 f2bf(float f) {
  u32 x = __float_as_uint(f);
  return (u16)((x + 0x7fffu + ((x >> 16) & 1u)) >> 16);
}
__device__ __forceinline__ u32 pk2(float a, float b) {
  return (u32)f2bf(a) | ((u32)f2bf(b) << 16);
}

// ---------------------------------------------------------------------------
// Kernel 1 v3: depthwise 7x7 conv + bias -> fp32 hw, bf16 vb, fp32 vsum.
// ONE WAVE PER (window, channel); thread owns a 4x4 output tile.
// wf in 49 registers (static idx via full unroll); patch rows read as 3
// aligned b128 per row (10 rows / 16 outputs) -> ~112 LDS instr/channel vs
// ~328 in the previous form. Barrier-free (wave-local LDS only).
// FMA order per output identical to prior rounds -> bit-identical hw/vb.
// ---------------------------------------------------------------------------
__global__ __launch_bounds__(256)
void dwconv_kernel(const float* __restrict__ x, const float* __restrict__ w,
                   const float* __restrict__ bias, float* __restrict__ hw,
                   u16* __restrict__ vb, float* __restrict__ vsum) {
  __shared__ float patch[4][38][40];   // per-wave; row stride 160B
  __shared__ float wfs[4][52];
  int tid = threadIdx.x;
  int lane = tid & 63, wv = tid >> 6;
  int blk = blockIdx.x;                // n*16 + cg
  int n = blk >> 4, c = ((blk & 15) << 2) + wv;
  int b = n >> 4, wy = (n >> 2) & 3, wx = n & 3;
  int y0 = wy * 32 - 3, x0 = wx * 32 - 3;

  if (lane < 49) wfs[wv][lane] = w[c * 49 + lane];

  // stage this wave's 38x38 halo patch (wave-local, no barrier needed)
  const float* xp = x + (size_t)(b * CC + c) * HH * WW;
  for (int i = lane; i < 38 * 38; i += 64) {
    int py = i / 38, px = i - py * 38;
    int gy = y0 + py, gx = x0 + px;
    float v = 0.f;
    if (gy >= 0 && gy < HH && gx >= 0 && gx < WW) v = xp[gy * WW + gx];
    patch[wv][py][px] = v;
  }

  // wf -> registers (static indices after unroll)
  float wreg[49];
  #pragma unroll
  for (int t = 0; t < 12; ++t) {
    float4 v4 = *(const float4*)&wfs[wv][t * 4];
    wreg[t * 4] = v4.x; wreg[t * 4 + 1] = v4.y;
    wreg[t * 4 + 2] = v4.z; wreg[t * 4 + 3] = v4.w;
  }
  wreg[48] = wfs[wv][48];

  int tx = lane & 7, ty = lane >> 3;   // 8x8 grid of 4x4 tiles
  float bv = bias[c];
  float acc[4][4];
  #pragma unroll
  for (int yi = 0; yi < 4; ++yi)
    #pragma unroll
    for (int xi = 0; xi < 4; ++xi) acc[yi][xi] = bv;

  // rows rr = 0..9 relative to tile origin; output y' gets dy = rr - y'
  #pragma unroll
  for (int rr = 0; rr < 10; ++rr) {
    const float* pr = &patch[wv][ty * 4 + rr][tx * 4];
    float4 ra = *(const float4*)pr;
    float4 rb = *(const float4*)(pr + 4);
    float4 rc = *(const float4*)(pr + 8);
    float rv[12] = {ra.x, ra.y, ra.z, ra.w, rb.x, rb.y, rb.z, rb.w,
                    rc.x, rc.y, rc.z, rc.w};
    #pragma unroll
    for (int yi = 0; yi < 4; ++yi) {
      if (rr >= yi && rr <= yi + 6) {
        int dy = rr - yi;
        #pragma unroll
        for (int dx = 0; dx < 7; ++dx) {
          float wgt = wreg[dy * 7 + dx];
          acc[yi][0] = fmaf(rv[dx],     wgt, acc[yi][0]);
          acc[yi][1] = fmaf(rv[dx + 1], wgt, acc[yi][1]);
          acc[yi][2] = fmaf(rv[dx + 2], wgt, acc[yi][2]);
          acc[yi][3] = fmaf(rv[dx + 3], wgt, acc[yi][3]);
        }
      }
    }
  }

  // stores + per-channel sum
  size_t obase = (size_t)(n * CC + c) * PP;
  float psum = 0.f;
  #pragma unroll
  for (int yi = 0; yi < 4; ++yi) {
    int oy = ty * 4 + yi;
    size_t off = obase + oy * 32 + tx * 4;
    *(float4*)(hw + off) = make_float4(acc[yi][0], acc[yi][1],
                                       acc[yi][2], acc[yi][3]);
    *(uint2*)(vb + off) = make_uint2(pk2(acc[yi][0], acc[yi][1]),
                                     pk2(acc[yi][2], acc[yi][3]));
    psum += (acc[yi][0] + acc[yi][1]) + (acc[yi][2] + acc[yi][3]);
  }
  #pragma unroll
  for (int off = 1; off < 64; off <<= 1) psum += __shfl_xor(psum, off);
  if (lane == 0) vsum[n * CC + c] = psum;
}

// ---------------------------------------------------------------------------
// Kernel 2 (MFMA, no LDS): q = 0.125*(W2 h + b2), k = W3 h + b3 -> bf16
// qT/kT[n][p][c]. Split-precision h (hi+lo bf16, 2 MFMAs). (unchanged, proven)
// ---------------------------------------------------------------------------
__global__ __launch_bounds__(256)
void qk_kernel(const float* __restrict__ hw,
               const float* __restrict__ w2, const float* __restrict__ b2,
               const float* __restrict__ w3, const float* __restrict__ b3,
               u16* __restrict__ qT, u16* __restrict__ kT) {
  int n = blockIdx.x >> 4;
  int chunk = blockIdx.x & 15;
  int tid = threadIdx.x;
  int lane = tid & 63, wvi = tid >> 6;
  int l31 = lane & 31, hi = lane >> 5;
  int phalf = wvi & 1, ochalf = wvi >> 1;
  int p0 = (chunk << 6) + (phalf << 5);
  int oc0 = ochalf << 5;

  union FU { u32 u[4]; s16x8 v; };

  s16x8 bq[4], bk[4];
  {
    const float* w2r = w2 + (oc0 + l31) * 64 + (hi << 3);
    const float* w3r = w3 + (oc0 + l31) * 64 + (hi << 3);
    #pragma unroll
    for (int kst = 0; kst < 4; ++kst) {
      float4 a = *(const float4*)(w2r + kst * 16);
      float4 b = *(const float4*)(w2r + kst * 16 + 4);
      FU f;
      f.u[0] = pk2(a.x * 0.125f, a.y * 0.125f);
      f.u[1] = pk2(a.z * 0.125f, a.w * 0.125f);
      f.u[2] = pk2(b.x * 0.125f, b.y * 0.125f);
      f.u[3] = pk2(b.z * 0.125f, b.w * 0.125f);
      bq[kst] = f.v;
      float4 c = *(const float4*)(w3r + kst * 16);
      float4 d = *(const float4*)(w3r + kst * 16 + 4);
      f.u[0] = pk2(c.x, c.y); f.u[1] = pk2(c.z, c.w);
      f.u[2] = pk2(d.x, d.y); f.u[3] = pk2(d.z, d.w);
      bk[kst] = f.v;
    }
  }

  f32x16 accq, acck;
  #pragma unroll
  for (int j = 0; j < 16; ++j) { accq[j] = 0.f; acck[j] = 0.f; }

  const float* hbase = hw + ((size_t)n << 16) + (size_t)(hi << 3) * PP
                       + p0 + l31;
  #pragma unroll
  for (int kst = 0; kst < 4; ++kst) {
    const float* hp = hbase + (size_t)(kst * 16) * PP;
    float h[8];
    #pragma unroll
    for (int e = 0; e < 8; ++e) h[e] = hp[e * PP];
    FU fh, fl;
    #pragma unroll
    for (int t = 0; t < 4; ++t) {
      u32 ph;
      asm("v_cvt_pk_bf16_f32 %0, %1, %2"
          : "=v"(ph) : "v"(h[2 * t]), "v"(h[2 * t + 1]));
      fh.u[t] = ph;
      float r0 = h[2 * t]     - __uint_as_float(ph << 16);
      float r1 = h[2 * t + 1] - __uint_as_float(ph & 0xffff0000u);
      u32 pl;
      asm("v_cvt_pk_bf16_f32 %0, %1, %2" : "=v"(pl) : "v"(r0), "v"(r1));
      fl.u[t] = pl;
    }
    accq = __builtin_amdgcn_mfma_f32_32x32x16_bf16(fh.v, bq[kst], accq, 0, 0, 0);
    accq = __builtin_amdgcn_mfma_f32_32x32x16_bf16(fl.v, bq[kst], accq, 0, 0, 0);
    acck = __builtin_amdgcn_mfma_f32_32x32x16_bf16(fh.v, bk[kst], acck, 0, 0, 0);
    acck = __builtin_amdgcn_mfma_f32_32x32x16_bf16(fl.v, bk[kst], acck, 0, 0, 0);
  }

  float biasq = b2[oc0 + l31] * 0.125f;
  float biask = b3[oc0 + l31];
  u16* qrow = qT + (((size_t)n << 10) + p0) * 64 + oc0 + l31;
  u16* krow = kT + (((size_t)n << 10) + p0) * 64 + oc0 + l31;
  #pragma unroll
  for (int r = 0; r < 16; ++r) {
    int pr = (r & 3) + ((r >> 2) << 3) + (hi << 2);
    qrow[pr * 64] = f2bf(accq[r] + biasq);
    krow[pr * 64] = f2bf(acck[r] + biask);
  }
}

// ---------------------------------------------------------------------------
// Kernel 3: LDS bf16 MFMA attention (P-1 decomposition) + fused conv4.
// (unchanged from R9, proven: Q-in-regs, K/V double-buffer, 1 barrier/pt)
// ---------------------------------------------------------------------------
__global__ __launch_bounds__(256)
void attn_kernel(const u16* __restrict__ qT, const u16* __restrict__ kT,
                 const u16* __restrict__ vB, const float* __restrict__ vsum,
                 const float* __restrict__ w4, const float* __restrict__ b4,
                 float* __restrict__ outp) {
  int bid = blockIdx.x;
  int w = (bid & 7) * 64 + (bid >> 3);
  int n = w >> 3, qb = w & 7;
  int tid = threadIdx.x;

  __shared__ __align__(16) unsigned char KsB[2][8192];  // K^T[p=64][c=64] dbuf
  __shared__ __align__(16) unsigned char VsB[2][8192];  // V[c=64][p=64] dbuf
  __shared__ __align__(16) unsigned char Osm[16384];    // O[q=128][c=64] bf16
  __shared__ float l_inv[4][32];

  int lane = tid & 63, wv = tid >> 6;
  int l31 = lane & 31, hi = lane >> 5;
  int sz = (lane & 7) << 4;
  int hi16 = hi << 4;

  const size_t nbase = (size_t)n << 16;   // n * 1024 * 64
  const u16* kg = kT + nbase;
  const u16* vg = vB + nbase;

  // ---- Q fragments once into registers (B-operand of S-MFMA) ----
  s16x8 qf[4];
  {
    const u16* qp = qT + nbase
                    + (size_t)((qb << 7) + (wv << 5) + l31) * 64 + (hi << 3);
    #pragma unroll
    for (int kc = 0; kc < 4; ++kc) qf[kc] = *(const s16x8*)(qp + kc * 16);
  }

  // ---- per-thread staging slots (2 x 16B for K, 2 x 16B for V) ----
  int i0 = tid, i1 = tid + 256;
  int row0 = i0 >> 3, c80 = i0 & 7;
  int row1 = i1 >> 3, c81 = i1 & 7;
  int dst0 = row0 * 128 + ((c80 * 16) ^ ((row0 & 7) << 4));
  int dst1 = row1 * 128 + ((c81 * 16) ^ ((row1 & 7) << 4));
  const u16* ks0 = kg + (size_t)row0 * 64 + c80 * 8;
  const u16* ks1 = kg + (size_t)row1 * 64 + c81 * 8;
  const u16* vs0 = vg + (size_t)row0 * 1024 + c80 * 8;
  const u16* vs1 = vg + (size_t)row1 * 1024 + c81 * 8;

  // ---- prologue: stage tile 0 into buffer 0 ----
  {
    uint4 ka = *(const uint4*)ks0;
    uint4 kb = *(const uint4*)ks1;
    uint4 va = *(const uint4*)vs0;
    uint4 vbx = *(const uint4*)vs1;
    *(uint4*)(KsB[0] + dst0) = ka;
    *(uint4*)(KsB[0] + dst1) = kb;
    *(uint4*)(VsB[0] + dst0) = va;
    *(uint4*)(VsB[0] + dst1) = vbx;
  }
  __syncthreads();

  f32x16 o0, o1;
  #pragma unroll
  for (int j = 0; j < 16; ++j) { o0[j] = 0.f; o1[j] = 0.f; }
  float lsum = 0.f;

  int cur = 0;
  for (int pt = 0; pt < 16; ++pt) {
    uint4 ka, kb, va, vbx;
    if (pt < 15) {
      size_t pn = (size_t)((pt + 1) << 6);
      ka  = *(const uint4*)(ks0 + pn * 64);
      kb  = *(const uint4*)(ks1 + pn * 64);
      va  = *(const uint4*)(vs0 + pn);
      vbx = *(const uint4*)(vs1 + pn);
    }

    const unsigned char* Kc = KsB[cur];
    const unsigned char* Vc = VsB[cur];

    // ---- S = K^T Q : two 32-p chunks ----
    f32x16 s0, s1;
    #pragma unroll
    for (int j = 0; j < 16; ++j) { s0[j] = 0.f; s1[j] = 0.f; }
    #pragma unroll
    for (int kc = 0; kc < 4; ++kc) {
      int cb = kc * 32 + hi16;
      s16x8 a0 = *(const s16x8*)(Kc + l31 * 128 + (cb ^ sz));
      s16x8 a1 = *(const s16x8*)(Kc + (32 + l31) * 128 + (cb ^ sz));
      s0 = __builtin_amdgcn_mfma_f32_32x32x16_bf16(a0, qf[kc], s0, 0, 0, 0);
      s1 = __builtin_amdgcn_mfma_f32_32x32x16_bf16(a1, qf[kc], s1, 0, 0, 0);
    }

    // ---- P_dev = exp(S)-1 ; l += exp(S) ----
    #pragma unroll
    for (int j = 0; j < 16; ++j) {
      float e = __expf(s0[j]); lsum += e; s0[j] = e - 1.0f;
    }
    #pragma unroll
    for (int j = 0; j < 16; ++j) {
      float e = __expf(s1[j]); lsum += e; s1[j] = e - 1.0f;
    }

    // ---- pack P_dev -> bf16 A-fragments of P_dev^T ----
    u32 t0,t1,t2,t3,t4,t5,t6,t7, u0,u1,u2,u3,u4,u5,u6,u7;
#define CVT(d, a, b) asm("v_cvt_pk_bf16_f32 %0, %1, %2" : "=v"(d) : "v"(a), "v"(b))
#define SWP(a, b)    asm("v_permlane32_swap_b32 %0, %1" : "+v"(a), "+v"(b))
    CVT(t0, s0[0],  s0[1]);  CVT(t1, s0[2],  s0[3]);
    CVT(t2, s0[4],  s0[5]);  CVT(t3, s0[6],  s0[7]);
    CVT(t4, s0[8],  s0[9]);  CVT(t5, s0[10], s0[11]);
    CVT(t6, s0[12], s0[13]); CVT(t7, s0[14], s0[15]);
    SWP(t0, t2); SWP(t1, t3); SWP(t4, t6); SWP(t5, t7);
    CVT(u0, s1[0],  s1[1]);  CVT(u1, s1[2],  s1[3]);
    CVT(u2, s1[4],  s1[5]);  CVT(u3, s1[6],  s1[7]);
    CVT(u4, s1[8],  s1[9]);  CVT(u5, s1[10], s1[11]);
    CVT(u6, s1[12], s1[13]); CVT(u7, s1[14], s1[15]);
    SWP(u0, u2); SWP(u1, u3); SWP(u4, u6); SWP(u5, u7);
#undef CVT
#undef SWP
    union FU { u32 u[4]; s16x8 v; };
    FU fA; fA.u[0]=t0; fA.u[1]=t1; fA.u[2]=t2; fA.u[3]=t3;  // p 0..15
    FU fB; fB.u[0]=t4; fB.u[1]=t5; fB.u[2]=t6; fB.u[3]=t7;  // p 16..31
    FU fC; fC.u[0]=u0; fC.u[1]=u1; fC.u[2]=u2; fC.u[3]=u3;  // p 32..47
    FU fD; fD.u[0]=u4; fD.u[1]=u5; fD.u[2]=u6; fD.u[3]=u7;  // p 48..63

    // ---- O^T += P_dev^T @ V^T ----
#define PV_STEP(frag, pb) do { \
      s16x8 bv0 = *(const s16x8*)(Vc + l31 * 128 + ((pb) ^ sz)); \
      s16x8 bv1 = *(const s16x8*)(Vc + (32 + l31) * 128 + ((pb) ^ sz)); \
      o0 = __builtin_amdgcn_mfma_f32_32x32x16_bf16(frag, bv0, o0, 0, 0, 0); \
      o1 = __builtin_amdgcn_mfma_f32_32x32x16_bf16(frag, bv1, o1, 0, 0, 0); \
    } while (0)
    PV_STEP(fA.v, 0 + hi16);
    PV_STEP(fB.v, 32 + hi16);
    PV_STEP(fC.v, 64 + hi16);
    PV_STEP(fD.v, 96 + hi16);
#undef PV_STEP

    // ---- write next tile into alternate buffer, single barrier ----
    if (pt < 15) {
      *(uint4*)(KsB[cur ^ 1] + dst0) = ka;
      *(uint4*)(KsB[cur ^ 1] + dst1) = kb;
      *(uint4*)(VsB[cur ^ 1] + dst0) = va;
      *(uint4*)(VsB[cur ^ 1] + dst1) = vbx;
      __syncthreads();
      cur ^= 1;
    }
  }

  // ---- softmax denominator ----
  lsum += __shfl_xor(lsum, 32);
  if (hi == 0) l_inv[wv][l31] = 1.0f / lsum;

  // ---- O_final = (vsum + o)/l as bf16 into Osm (wave-private rows) ----
  float vsa = vsum[(n << 6) + l31];
  float vsb = vsum[(n << 6) + 32 + l31];
  int g0 = l31 >> 3, g1 = (32 + l31) >> 3;
  int bi = (l31 & 7) << 1;
  #pragma unroll
  for (int r = 0; r < 16; ++r) {
    int qr = (r & 3) + ((r >> 2) << 3) + (hi << 2);
    int row = (wv << 5) + qr;
    float li = l_inv[wv][qr];
    int rs = (row & 7) << 4;
    *(u16*)(Osm + row * 128 + ((g0 << 4) ^ rs) + bi) = f2bf((vsa + o0[r]) * li);
    *(u16*)(Osm + row * 128 + ((g1 << 4) ^ rs) + bi) = f2bf((vsb + o1[r]) * li);
  }
  // no barrier: each wave reads only its own rows below

  // ---- fused conv4: D2[oc][q] = sum_c W4[oc][c] * Ofinal[q][c] ----
  union FU2 { u32 u[4]; s16x8 v; };
  int orow = (wv << 5) + l31;
  int osw = (orow & 7) << 4;
  s16x8 bf[4];
  #pragma unroll
  for (int kst = 0; kst < 4; ++kst)
    bf[kst] = *(const s16x8*)(Osm + orow * 128 + ((((kst << 1) + hi) << 4) ^ osw));

  f32x16 d2a, d2b;
  #pragma unroll
  for (int j = 0; j < 16; ++j) { d2a[j] = 0.f; d2b[j] = 0.f; }
  {
    const float* w4r = w4 + l31 * 64 + (hi << 3);          // oc-half 0
    #pragma unroll
    for (int kst = 0; kst < 4; ++kst) {
      float4 a = *(const float4*)(w4r + kst * 16);
      float4 b = *(const float4*)(w4r + kst * 16 + 4);
      FU2 f;
      f.u[0] = pk2(a.x, a.y); f.u[1] = pk2(a.z, a.w);
      f.u[2] = pk2(b.x, b.y); f.u[3] = pk2(b.z, b.w);
      d2a = __builtin_amdgcn_mfma_f32_32x32x16_bf16(f.v, bf[kst], d2a, 0, 0, 0);
    }
    const float* w4r2 = w4 + (32 + l31) * 64 + (hi << 3);  // oc-half 1
    #pragma unroll
    for (int kst = 0; kst < 4; ++kst) {
      float4 a = *(const float4*)(w4r2 + kst * 16);
      float4 b = *(const float4*)(w4r2 + kst * 16 + 4);
      FU2 f;
      f.u[0] = pk2(a.x, a.y); f.u[1] = pk2(a.z, a.w);
      f.u[2] = pk2(b.x, b.y); f.u[3] = pk2(b.z, b.w);
      d2b = __builtin_amdgcn_mfma_f32_32x32x16_bf16(f.v, bf[kst], d2b, 0, 0, 0);
    }
  }

  // ---- store NCHW: p = qb*128 + wv*32 + l31 -> y fixed/wave, x = wx*32+l31
  int b_ = n >> 4, wy = (n >> 2) & 3, wx = n & 3;
  int y = wy * 32 + (qb << 2) + wv;
  int x = wx * 32 + l31;
  float* obase = outp + ((size_t)b_ * CC * HH + y) * WW + x;
  #pragma unroll
  for (int r = 0; r < 16; ++r) {
    int ocr = (r & 3) + ((r >> 2) << 3) + (hi << 2);
    obase[(size_t)ocr * HH * WW]        = d2a[r] + b4[ocr];
    obase[(size_t)(32 + ocr) * HH * WW] = d2b[r] + b4[32 + ocr];
  }
}

// ---------------------------------------------------------------------------
extern "C" void kernel_launch(void* const* d_in, const int* in_sizes, int n_in,
                              void* d_out, int out_size, void* d_ws, size_t ws_size,
                              hipStream_t stream) {
  const float* x  = (const float*)d_in[0];
  const float* w1 = (const float*)d_in[1];
  const float* b1 = (const float*)d_in[2];
  const float* w2 = (const float*)d_in[3];
  const float* b2 = (const float*)d_in[4];
  const float* w3 = (const float*)d_in[5];
  const float* b3 = (const float*)d_in[6];
  const float* w4 = (const float*)d_in[7];
  const float* b4 = (const float*)d_in[8];
  float* outp = (float*)d_out;

  char* wsb = (char*)d_ws;
  float* hw   = (float*)wsb;                       // 16 MiB fp32 [n][c][p]
  u16*   qT   = (u16*)(wsb + (16u << 20));         //  8 MiB bf16 [n][p][c]
  u16*   kT   = (u16*)(wsb + (24u << 20));         //  8 MiB bf16 [n][p][c]
  u16*   vb   = (u16*)(wsb + (32u << 20));         //  8 MiB bf16 [n][c][p]
  float* vsum = (float*)(wsb + (40u << 20));       // 16 KiB fp32 [n][c]

  dwconv_kernel<<<NWIN * 16, 256, 0, stream>>>(x, w1, b1, hw, vb, vsum);
  qk_kernel   <<<NWIN * 16, 256, 0, stream>>>(hw, w2, b2, w3, b3, qT, kT);
  attn_kernel <<<NWIN * 8,  256, 0, stream>>>(qT, kT, vb, vsum, w4, b4, outp);
}